// Round 3
// baseline (85958.936 us; speedup 1.0000x reference)
//
#include <hip/hip_runtime.h>
#include <hip/hip_bf16.h>
#include <math.h>

#define T_STEPS 8192
#define M_DIM   1024
#define N_DIM   2048

// ---------------- Kernel A: pre = X @ W_ih^T + (b_ih + b_hh) ----------------
// Written into d_out (consumed in-place by the recurrence kernel).
// 128x128 tile, BK=32, 256 threads, 8x8 micro-tile, fp32 SIMT.
__global__ __launch_bounds__(256) void pre_gemm(
    const float* __restrict__ X, const float* __restrict__ Wih,
    const float* __restrict__ bih, const float* __restrict__ bhh,
    float* __restrict__ out)
{
  __shared__ float As[128][36];   // +4 pad keeps float4 alignment, breaks pow2 stride
  __shared__ float Bs[128][36];
  const int tid = threadIdx.x;
  const int tx = tid & 15;        // col group (n)
  const int ty = tid >> 4;        // row group (t)
  const int bt = blockIdx.x * 128;
  const int bn = blockIdx.y * 128;

  float acc[8][8];
  #pragma unroll
  for (int i = 0; i < 8; ++i)
    #pragma unroll
    for (int j = 0; j < 8; ++j) acc[i][j] = 0.f;

  for (int k0 = 0; k0 < M_DIM; k0 += 32) {
    #pragma unroll
    for (int s = 0; s < 4; ++s) {
      int slot = tid + s * 256;           // 1024 float4 slots per operand
      int row  = slot >> 3;
      int c4   = (slot & 7) << 2;
      float4 va = *(const float4*)&X  [(size_t)(bt + row) * M_DIM + k0 + c4];
      float4 vb = *(const float4*)&Wih[(size_t)(bn + row) * M_DIM + k0 + c4];
      *(float4*)&As[row][c4] = va;
      *(float4*)&Bs[row][c4] = vb;
    }
    __syncthreads();
    #pragma unroll
    for (int kk = 0; kk < 32; kk += 4) {
      float4 a4[8], b4[8];
      #pragma unroll
      for (int i = 0; i < 8; ++i) a4[i] = *(const float4*)&As[ty + 16 * i][kk];
      #pragma unroll
      for (int j = 0; j < 8; ++j) b4[j] = *(const float4*)&Bs[tx + 16 * j][kk];
      #pragma unroll
      for (int i = 0; i < 8; ++i)
        #pragma unroll
        for (int j = 0; j < 8; ++j) {
          acc[i][j] = fmaf(a4[i].x, b4[j].x, acc[i][j]);
          acc[i][j] = fmaf(a4[i].y, b4[j].y, acc[i][j]);
          acc[i][j] = fmaf(a4[i].z, b4[j].z, acc[i][j]);
          acc[i][j] = fmaf(a4[i].w, b4[j].w, acc[i][j]);
        }
    }
    __syncthreads();
  }

  float bsum[8];
  #pragma unroll
  for (int j = 0; j < 8; ++j) {
    int col = bn + tx + 16 * j;
    bsum[j] = bih[col] + bhh[col];
  }
  #pragma unroll
  for (int i = 0; i < 8; ++i) {
    int rowg = bt + ty + 16 * i;
    #pragma unroll
    for (int j = 0; j < 8; ++j)
      out[(size_t)rowg * N_DIM + bn + tx + 16 * j] = acc[i][j] + bsum[j];
  }
}

// ---------------- Kernel B: persistent recurrence ----------------
// 256 blocks (1/CU) x 256 threads. Block b owns rows [8b, 8b+8) of W_hh,
// held in registers: thread (r = tid>>5, c = tid&31) keeps W[8b+r][c+32k],
// k = 0..63 (64 VGPRs). Per step: all blocks exchange h via LLC (agent-scope
// atomics) guarded by a 16-leaf monotonic counter barrier.
// Counter signal is RELEASE (after vmcnt(0) h-store drain); spin load is
// ACQUIRE — proper happens-before chain across XCDs (G16).
__global__ __launch_bounds__(256) void rnn_persist(
    const float* __restrict__ Whh,
    float* __restrict__ Y,        // d_out: holds pre[t] until step t overwrites with h_t
    float* __restrict__ hbuf,     // 2 * N_DIM floats (double buffer), zeroed => h_0 = 0
    int* __restrict__ cnt)        // 16 counters spaced 32 ints (128B), zeroed
{
  __shared__ float h_lds[N_DIM];
  const int tid  = threadIdx.x;
  const int b    = blockIdx.x;
  const int r    = tid >> 5;
  const int c    = tid & 31;
  const int grow = b * 8 + r;     // global output row

  float w[64];
  #pragma unroll
  for (int k = 0; k < 64; ++k)
    w[k] = Whh[(size_t)grow * N_DIM + c + 32 * k];

  for (int t = 0; t < T_STEPS; ++t) {
    // pre[t] for this row: issue before the spin so latency hides under it
    float prev_pre = 0.f;
    if (c == 0) prev_pre = Y[(size_t)t * N_DIM + grow];

    // wait until all 256 blocks published h_{t-1}: every leaf counter >= 16*t
    if (tid < 64) {
      const int target = 16 * t;
      while (true) {
        int v = 0x7FFFFFFF;
        if (tid < 16)
          v = __hip_atomic_load(&cnt[tid * 32], __ATOMIC_ACQUIRE, __HIP_MEMORY_SCOPE_AGENT);
        if (__ballot(v >= target) == 0xFFFFFFFFFFFFFFFFull) break;
        __builtin_amdgcn_s_sleep(1);
      }
    }
    __syncthreads();

    // stage h_{t-1} (coalesced, L1-bypassing loads from the coherent point)
    const float* __restrict__ hsrc = hbuf + (t & 1) * N_DIM;
    float* __restrict__ hdst       = hbuf + ((t + 1) & 1) * N_DIM;
    #pragma unroll
    for (int i = 0; i < 8; ++i) {
      int idx = tid + 256 * i;
      float v = __hip_atomic_load(&hsrc[idx], __ATOMIC_RELAXED, __HIP_MEMORY_SCOPE_AGENT);
      h_lds[idx] = v;
    }
    __syncthreads();

    // y[grow] = sum_j W[grow][j] * h[j]   (j = c + 32k lanes, conflict-free LDS)
    float acc = 0.f;
    #pragma unroll
    for (int k = 0; k < 64; ++k)
      acc = fmaf(w[k], h_lds[c + 32 * k], acc);

    // reduce across the 32 lanes of this row (stays within 32-aligned group)
    #pragma unroll
    for (int off = 16; off >= 1; off >>= 1)
      acc += __shfl_xor(acc, off, 64);

    if (c == 0) {
      float hn = tanhf(acc + prev_pre);
      Y[(size_t)t * N_DIM + grow] = hn;                       // output Y[t]
      __hip_atomic_store(&hdst[grow], hn, __ATOMIC_RELAXED,   // publish h_t
                         __HIP_MEMORY_SCOPE_AGENT);
    }
    // drain h stores to the coherent point before signaling
    asm volatile("s_waitcnt vmcnt(0)" ::: "memory");
    __syncthreads();
    if (tid == 0)
      __hip_atomic_fetch_add(&cnt[(b & 15) * 32], 1, __ATOMIC_RELEASE,
                             __HIP_MEMORY_SCOPE_AGENT);
  }
}

extern "C" void kernel_launch(void* const* d_in, const int* in_sizes, int n_in,
                              void* d_out, int out_size, void* d_ws, size_t ws_size,
                              hipStream_t stream) {
  const float* X   = (const float*)d_in[0];
  const float* Wih = (const float*)d_in[1];
  const float* Whh = (const float*)d_in[2];
  const float* bih = (const float*)d_in[3];
  const float* bhh = (const float*)d_in[4];
  float* Y = (float*)d_out;

  float* hbuf = (float*)d_ws;                       // 2 * 2048 floats = 16 KB
  int*   cnt  = (int*)((char*)d_ws + 16384);        // 16 counters x 128B = 2 KB

  // zero h double-buffer (h_0 = 0) and barrier counters (ws is poisoned 0xAA)
  hipMemsetAsync(d_ws, 0, 16384 + 2048, stream);

  dim3 gA(T_STEPS / 128, N_DIM / 128);              // (64, 16)
  pre_gemm<<<gA, dim3(256), 0, stream>>>(X, Wih, bih, bhh, Y);

  rnn_persist<<<dim3(256), dim3(256), 0, stream>>>(Whh, Y, hbuf, cnt);
}

// Round 4
// 35471.652 us; speedup vs baseline: 2.4233x; 2.4233x over previous
//
#include <hip/hip_runtime.h>
#include <hip/hip_bf16.h>
#include <math.h>

#define T_STEPS 8192
#define M_DIM   1024
#define N_DIM   2048

typedef unsigned long long u64;

// ---------------- Kernel A: pre = X @ W_ih^T + (b_ih + b_hh) ----------------
// Written into d_out (consumed in-place by the recurrence kernel).
// 128x128 tile, BK=32, 256 threads, 8x8 micro-tile, fp32 SIMT.
__global__ __launch_bounds__(256) void pre_gemm(
    const float* __restrict__ X, const float* __restrict__ Wih,
    const float* __restrict__ bih, const float* __restrict__ bhh,
    float* __restrict__ out)
{
  __shared__ float As[128][36];   // +4 pad keeps float4 alignment, breaks pow2 stride
  __shared__ float Bs[128][36];
  const int tid = threadIdx.x;
  const int tx = tid & 15;        // col group (n)
  const int ty = tid >> 4;        // row group (t)
  const int bt = blockIdx.x * 128;
  const int bn = blockIdx.y * 128;

  float acc[8][8];
  #pragma unroll
  for (int i = 0; i < 8; ++i)
    #pragma unroll
    for (int j = 0; j < 8; ++j) acc[i][j] = 0.f;

  for (int k0 = 0; k0 < M_DIM; k0 += 32) {
    #pragma unroll
    for (int s = 0; s < 4; ++s) {
      int slot = tid + s * 256;           // 1024 float4 slots per operand
      int row  = slot >> 3;
      int c4   = (slot & 7) << 2;
      float4 va = *(const float4*)&X  [(size_t)(bt + row) * M_DIM + k0 + c4];
      float4 vb = *(const float4*)&Wih[(size_t)(bn + row) * M_DIM + k0 + c4];
      *(float4*)&As[row][c4] = va;
      *(float4*)&Bs[row][c4] = vb;
    }
    __syncthreads();
    #pragma unroll
    for (int kk = 0; kk < 32; kk += 4) {
      float4 a4[8], b4[8];
      #pragma unroll
      for (int i = 0; i < 8; ++i) a4[i] = *(const float4*)&As[ty + 16 * i][kk];
      #pragma unroll
      for (int j = 0; j < 8; ++j) b4[j] = *(const float4*)&Bs[tx + 16 * j][kk];
      #pragma unroll
      for (int i = 0; i < 8; ++i)
        #pragma unroll
        for (int j = 0; j < 8; ++j) {
          acc[i][j] = fmaf(a4[i].x, b4[j].x, acc[i][j]);
          acc[i][j] = fmaf(a4[i].y, b4[j].y, acc[i][j]);
          acc[i][j] = fmaf(a4[i].z, b4[j].z, acc[i][j]);
          acc[i][j] = fmaf(a4[i].w, b4[j].w, acc[i][j]);
        }
    }
    __syncthreads();
  }

  float bsum[8];
  #pragma unroll
  for (int j = 0; j < 8; ++j) {
    int col = bn + tx + 16 * j;
    bsum[j] = bih[col] + bhh[col];
  }
  #pragma unroll
  for (int i = 0; i < 8; ++i) {
    int rowg = bt + ty + 16 * i;
    #pragma unroll
    for (int j = 0; j < 8; ++j)
      out[(size_t)rowg * N_DIM + bn + tx + 16 * j] = acc[i][j] + bsum[j];
  }
}

// ---------------- Kernel B: persistent recurrence, tagged dataflow ----------
// 256 blocks x 256 threads; block b owns rows [8b,8b+8) of W_hh in registers.
// h exchanged as atomic 64-bit {tag,value} pairs in a double-buffered slot
// array (the store IS the signal — no barrier, no fences, no cache
// maintenance; all atomics RELAXED agent-scope = sc-bit bypass to the
// coherent point). Max inter-block skew is 1 step by construction (entering
// step t requires all tags >= t, i.e. every block finished t-1), which makes
// the 2-buffer rotation race-free.
__global__ __launch_bounds__(256) void rnn_persist(
    const float* __restrict__ Whh,
    float* __restrict__ Y,        // d_out: holds pre[t] until step t overwrites with h_{t+1}
    u64* __restrict__ hbuf)       // 2 * N_DIM tagged slots {tag<<32 | f32bits}, zeroed
{
  __shared__ float h_lds[N_DIM];
  const int tid  = threadIdx.x;
  const int b    = blockIdx.x;
  const int r    = tid >> 5;
  const int c    = tid & 31;
  const int grow = b * 8 + r;     // global output row

  float w[64];
  #pragma unroll
  for (int k = 0; k < 64; ++k)
    w[k] = Whh[(size_t)grow * N_DIM + c + 32 * k];

  for (int t = 0; t < T_STEPS; ++t) {
    // pre[t] for this row (plain cached load; latency hides under the poll)
    float prev_pre = 0.f;
    if (c == 0) prev_pre = Y[(size_t)t * N_DIM + grow];

    u64* __restrict__ src = hbuf + (t & 1) * N_DIM;         // h_t slots (tag t)
    u64* __restrict__ dst = hbuf + ((t + 1) & 1) * N_DIM;   // h_{t+1} slots
    const unsigned need = (unsigned)t;

    // poll this thread's 8 slots until their tags reach t (coalesced 8B loads)
    float hv[8];
    unsigned pending = 0xffu;
    while (pending) {
      #pragma unroll
      for (int i = 0; i < 8; ++i)
        if (pending & (1u << i)) {
          u64 p = __hip_atomic_load(&src[tid + 256 * i], __ATOMIC_RELAXED,
                                    __HIP_MEMORY_SCOPE_AGENT);
          if ((unsigned)(p >> 32) >= need) {
            hv[i] = __uint_as_float((unsigned)(p & 0xffffffffu));
            pending &= ~(1u << i);
          }
        }
    }
    #pragma unroll
    for (int i = 0; i < 8; ++i) h_lds[tid + 256 * i] = hv[i];
    __syncthreads();

    // y[grow] = sum_j W[grow][j] * h[j]   (j = c + 32k lanes, conflict-free LDS)
    float acc = 0.f;
    #pragma unroll
    for (int k = 0; k < 64; ++k)
      acc = fmaf(w[k], h_lds[c + 32 * k], acc);

    // reduce across the 32 lanes of this row (XOR stays within 32-group)
    #pragma unroll
    for (int off = 16; off >= 1; off >>= 1)
      acc += __shfl_xor(acc, off, 64);

    if (c == 0) {
      float hn = tanhf(acc + prev_pre);
      // Y[t] = h_{t+1}; write-through atomic avoids cross-XCD dirty-line aliasing
      __hip_atomic_store(&Y[(size_t)t * N_DIM + grow], hn, __ATOMIC_RELAXED,
                         __HIP_MEMORY_SCOPE_AGENT);
      u64 pk = ((u64)(unsigned)(t + 1) << 32) | (u64)__float_as_uint(hn);
      __hip_atomic_store(&dst[grow], pk, __ATOMIC_RELAXED,
                         __HIP_MEMORY_SCOPE_AGENT);
    }
    // protect h_lds: no thread may overwrite (next step) while others still read
    __syncthreads();
  }
}

extern "C" void kernel_launch(void* const* d_in, const int* in_sizes, int n_in,
                              void* d_out, int out_size, void* d_ws, size_t ws_size,
                              hipStream_t stream) {
  const float* X   = (const float*)d_in[0];
  const float* Wih = (const float*)d_in[1];
  const float* Whh = (const float*)d_in[2];
  const float* bih = (const float*)d_in[3];
  const float* bhh = (const float*)d_in[4];
  float* Y = (float*)d_out;

  u64* hbuf = (u64*)d_ws;   // 2 * 2048 tagged slots = 32 KB

  // zero tagged slots: tag 0 + value 0.0 == h_0 (ws is re-poisoned 0xAA each run)
  hipMemsetAsync(d_ws, 0, 2 * N_DIM * sizeof(u64), stream);

  dim3 gA(T_STEPS / 128, N_DIM / 128);              // (64, 16)
  pre_gemm<<<gA, dim3(256), 0, stream>>>(X, Wih, bih, bhh, Y);

  rnn_persist<<<dim3(256), dim3(256), 0, stream>>>(Whh, Y, hbuf);
}